// Round 7
// baseline (10040.540 us; speedup 1.0000x reference)
//
#include <hip/hip_runtime.h>

// LSTM T=16384, B=32, H=96. One block per batch (32 blocks x 768 threads).
// R6 post-mortem: VALUBusy math showed ~180 VALU instr/thread/step -> the
// __builtin_amdgcn_fdot2 guard silently fell back to scalar cvt+fma (4 instr
// per f16 pair + per-step W conversion). This round: inline-asm
// v_dot2_f32_f16 (VOP3P packed dot, fp32 acc) -> 24 dot instr/thread/step.
// Structure unchanged from R6 (passed, 9.77ms): thread (j=tid>>3, s=tid&7)
// computes all 4 gates of cell j over k-slice [12s,12s+12); DPP butterfly
// (quad_perm xor1/xor2 + row_half_mirror) reduces the 8 slice lanes on the
// VALU pipe; lane s==0 does the c/h update in-register; ONE barrier/step.
// h history f16 in a 512-step rolling LDS buffer; fc projection bulk-flushed
// every 512 steps.

constexpr int HH  = 96;
constexpr int BB  = 32;
constexpr int TT  = 16384;
constexpr int TH  = 768;    // 12 waves
constexpr int NS  = 512;    // h history window
constexpr int ROWP = 100;   // halves per hist row (padded)
constexpr int CH  = 2048;   // x chunk in LDS

typedef _Float16 f16x2 __attribute__((ext_vector_type(2)));

// Guaranteed single-instruction packed dot: d = a.x*b.x + a.y*b.y + c (fp32).
__device__ __forceinline__ float dot2_f16(f16x2 a, f16x2 b, float c) {
    float d;
    int ai = __builtin_bit_cast(int, a);
    int bi = __builtin_bit_cast(int, b);
    asm("v_dot2_f32_f16 %0, %1, %2, %3" : "=v"(d) : "v"(ai), "v"(bi), "v"(c));
    return d;
}

// VALU cross-lane add via DPP16 (no DS pipe).
template <int CTRL>
__device__ __forceinline__ float dpp_add(float v) {
    int r = __builtin_amdgcn_update_dpp(0, __builtin_bit_cast(int, v),
                                        CTRL, 0xF, 0xF, true);
    return v + __builtin_bit_cast(float, r);
}
constexpr int DPP_XOR1 = 0xB1;  // quad_perm [1,0,3,2]
constexpr int DPP_XOR2 = 0x4E;  // quad_perm [2,3,0,1]
constexpr int DPP_HMIR = 0x141; // row_half_mirror: lane i <-> 7-i in each 8

__device__ __forceinline__ float sigm(float v) {
    return __builtin_amdgcn_rcpf(1.0f + __expf(-v));
}
__device__ __forceinline__ float tanh_f(float v) {
    return fmaf(2.0f, __builtin_amdgcn_rcpf(1.0f + __expf(-2.0f * v)), -1.0f);
}

__attribute__((amdgpu_flat_work_group_size(TH, TH), amdgpu_waves_per_eu(3, 3)))
__global__ void lstm_kernel(const float* __restrict__ x,
                            const float* __restrict__ w_ih,
                            const float* __restrict__ w_hh,
                            const float* __restrict__ b_ih,
                            const float* __restrict__ b_hh,
                            const float* __restrict__ fc_w,
                            const float* __restrict__ fc_b,
                            float* __restrict__ out) {
    __shared__ _Float16 hist[NS * ROWP];  // 100 KB rolling h history (f16)
    __shared__ float xs[CH];              // 8 KB x chunk
    __shared__ float fcw_s[HH];

    const int tid  = threadIdx.x;
    const int b    = blockIdx.x;
    const int j    = tid >> 3;   // cell 0..95
    const int s    = tid & 7;    // k-slice: k in [12s, 12s+12)
    const bool lead = (s == 0);

    // ---- one-time: pack w_hh[(g*96+j)][12s..12s+12) as 24 f16x2 VGPRs ----
    f16x2 W[4][6];
#pragma unroll
    for (int g = 0; g < 4; ++g) {
        const float* wr = w_hh + (g * HH + j) * HH + 12 * s;
#pragma unroll
        for (int m = 0; m < 6; ++m)
            W[g][m] = f16x2{(_Float16)wr[2 * m], (_Float16)wr[2 * m + 1]};
    }
#pragma unroll
    for (int g = 0; g < 4; ++g)
#pragma unroll
        for (int m = 0; m < 6; ++m) asm volatile("" : "+v"(W[g][m]));

    float wih[4], bias[4];
#pragma unroll
    for (int g = 0; g < 4; ++g) {
        wih[g]  = w_ih[g * HH + j];
        bias[g] = b_ih[g * HH + j] + b_hh[g * HH + j];
    }
    const float fcb = fc_b[0];
    float c = 0.0f;

    for (int i = tid; i < HH; i += TH) {
        fcw_s[i] = fc_w[i];
        hist[(NS - 1) * ROWP + i] = (_Float16)0.0f;  // h(-1) = 0
    }

    // Bulk fc projection for steps [t0, t0+NS): out = hist.fcw + fcb + x
    auto flush = [&](int t0) {
        if (tid < NS) {
            const uint2* hr = (const uint2*)(hist + tid * ROWP);
            float a = 0.0f;
#pragma unroll
            for (int m = 0; m < 24; ++m) {
                uint2 u = hr[m];
                f16x2 p0 = __builtin_bit_cast(f16x2, u.x);
                f16x2 p1 = __builtin_bit_cast(f16x2, u.y);
                a = fmaf((float)p0.x, fcw_s[4 * m + 0], a);
                a = fmaf((float)p0.y, fcw_s[4 * m + 1], a);
                a = fmaf((float)p1.x, fcw_s[4 * m + 2], a);
                a = fmaf((float)p1.y, fcw_s[4 * m + 3], a);
            }
            out[(t0 + tid) * BB + b] = a + fcb + xs[(t0 + tid) & (CH - 1)];
        }
    };

    for (int t = 0; t < TT; ++t) {
        if (t > 0 && (t & (NS - 1)) == 0) {   // flush BEFORE any xs refill
            flush(t - NS);
            __syncthreads();
        }
        if ((t & (CH - 1)) == 0) {            // covers t=0 (also init barrier)
            for (int i = tid; i < CH; i += TH) xs[i] = x[(t + i) * BB + b];
            __syncthreads();
        }

        // ---- gate dots: 4 gates x 6 v_dot2 over h(t-1) slice ----
        const int pr = (t - 1) & (NS - 1);    // t=0 -> 511 (zeros)
        const uint2* hrow =
            (const uint2*)((const uint32_t*)(hist + pr * ROWP) + 6 * s);
        uint2 ua = hrow[0], ub = hrow[1], uc = hrow[2];
        f16x2 h2[6] = {__builtin_bit_cast(f16x2, ua.x), __builtin_bit_cast(f16x2, ua.y),
                       __builtin_bit_cast(f16x2, ub.x), __builtin_bit_cast(f16x2, ub.y),
                       __builtin_bit_cast(f16x2, uc.x), __builtin_bit_cast(f16x2, uc.y)};
        const float xv = xs[t & (CH - 1)];

        float acc[4];
#pragma unroll
        for (int g = 0; g < 4; ++g) {
            acc[g] = lead ? fmaf(xv, wih[g], bias[g]) : 0.0f;
#pragma unroll
            for (int m = 0; m < 6; ++m) acc[g] = dot2_f16(W[g][m], h2[m], acc[g]);
        }

        // ---- reduce over the 8 slice lanes: VALU DPP, no DS pipe ----
#pragma unroll
        for (int g = 0; g < 4; ++g) {
            acc[g] = dpp_add<DPP_XOR1>(acc[g]);   // i ^= 1
            acc[g] = dpp_add<DPP_XOR2>(acc[g]);   // i ^= 2  (quad sums)
            acc[g] = dpp_add<DPP_HMIR>(acc[g]);   // 0<-7: other quad's sum
        }

        // ---- c/h update in-register on the lead lane; write h(t) ----
        if (lead) {
            const float iv = sigm(acc[0]);
            const float fv = sigm(acc[1]);
            const float gv = tanh_f(acc[2]);
            const float ov = sigm(acc[3]);
            c = fmaf(fv, c, iv * gv);
            const float h = ov * tanh_f(c);
            hist[(t & (NS - 1)) * ROWP + j] = (_Float16)h;
        }
        __syncthreads();   // h(t) visible; hist row t&511 overwrite safe
    }
    flush(TT - NS);        // last window (loop ended with a barrier)
}

extern "C" void kernel_launch(void* const* d_in, const int* in_sizes, int n_in,
                              void* d_out, int out_size, void* d_ws, size_t ws_size,
                              hipStream_t stream) {
    const float* x    = (const float*)d_in[0];
    const float* w_ih = (const float*)d_in[1];
    const float* w_hh = (const float*)d_in[2];
    const float* b_ih = (const float*)d_in[3];
    const float* b_hh = (const float*)d_in[4];
    const float* fc_w = (const float*)d_in[5];
    const float* fc_b = (const float*)d_in[6];
    float* out = (float*)d_out;

    lstm_kernel<<<dim3(BB), dim3(TH), 0, stream>>>(x, w_ih, w_hh, b_ih, b_hh,
                                                   fc_w, fc_b, out);
}

// Round 8
// 8196.051 us; speedup vs baseline: 1.2250x; 1.2250x over previous
//
#include <hip/hip_runtime.h>

// LSTM T=16384, B=32, H=96. One block per batch (32 blocks x 384 threads).
// R7 lesson: v_dot2 asm == builtin (no scalar fallback); the issue budget is
// dominated by per-wave overhead and the serial masked activation tail
// (10 quarter-rate trans ops/wave). This round: 4 threads/cell (6 waves).
// Thread (j=tid>>2, s=tid&3) computes all 4 gates of cell j over k-slice
// [24s,24s+24) halves (48 weight VGPRs, v_dot2_f32_f16, fp32 acc).
// 2-level DPP butterfly (xor1,xor2) -> every quad lane holds all 4 gate sums;
// lane s applies gate s's activation (4 activations in PARALLEL, 4 trans
// ops/wave instead of 10); lane 0 gathers f,g,o via quad_perm broadcasts and
// updates c/h in-register. Bias folded in after the reduce. One barrier/step.
// h history f16 in a 512-step rolling LDS buffer (rows 16B-aligned for
// ds_read_b128); fc projection bulk-flushed every 512 steps.

constexpr int HH   = 96;
constexpr int BB   = 32;
constexpr int TT   = 16384;
constexpr int TH   = 384;   // 6 waves
constexpr int NS   = 512;   // h history window
constexpr int ROWP = 104;   // halves per hist row: 208 B, 16B-aligned
constexpr int CH   = 2048;  // x chunk in LDS

typedef _Float16 f16x2 __attribute__((ext_vector_type(2)));

__device__ __forceinline__ float dot2_f16(f16x2 a, f16x2 b, float c) {
    float d;
    int ai = __builtin_bit_cast(int, a);
    int bi = __builtin_bit_cast(int, b);
    asm("v_dot2_f32_f16 %0, %1, %2, %3" : "=v"(d) : "v"(ai), "v"(bi), "v"(c));
    return d;
}

// Cross-lane via DPP quad_perm (VALU pipe, no DS).
template <int CTRL>
__device__ __forceinline__ float dpp_add(float v) {
    int r = __builtin_amdgcn_mov_dpp(__builtin_bit_cast(int, v), CTRL, 0xF, 0xF, true);
    return v + __builtin_bit_cast(float, r);
}
template <int CTRL>
__device__ __forceinline__ float dpp_bcast(float v) {
    int r = __builtin_amdgcn_mov_dpp(__builtin_bit_cast(int, v), CTRL, 0xF, 0xF, true);
    return __builtin_bit_cast(float, r);
}
constexpr int DPP_XOR1 = 0xB1;  // quad_perm [1,0,3,2]
constexpr int DPP_XOR2 = 0x4E;  // quad_perm [2,3,0,1]
constexpr int DPP_B1   = 0x55;  // quad_perm [1,1,1,1]
constexpr int DPP_B2   = 0xAA;  // quad_perm [2,2,2,2]
constexpr int DPP_B3   = 0xFF;  // quad_perm [3,3,3,3]

__device__ __forceinline__ float tanh_f(float v) {
    return fmaf(2.0f, __builtin_amdgcn_rcpf(1.0f + __expf(-2.0f * v)), -1.0f);
}

__attribute__((amdgpu_flat_work_group_size(TH, TH), amdgpu_waves_per_eu(1, 2)))
__global__ void lstm_kernel(const float* __restrict__ x,
                            const float* __restrict__ w_ih,
                            const float* __restrict__ w_hh,
                            const float* __restrict__ b_ih,
                            const float* __restrict__ b_hh,
                            const float* __restrict__ fc_w,
                            const float* __restrict__ fc_b,
                            float* __restrict__ out) {
    __shared__ _Float16 hist[NS * ROWP];  // ~106 KB rolling h history (f16)
    __shared__ float xs[CH];              // 8 KB x chunk
    __shared__ float fcw_s[HH];

    const int tid = threadIdx.x;
    const int b   = blockIdx.x;
    const int j   = tid >> 2;    // cell 0..95
    const int s   = tid & 3;     // k-slice [24s, 24s+24) halves; also "my gate"

    // ---- one-time: pack w_hh[(g*96+j)][24s..24s+24) as 48 f16x2 VGPRs ----
    f16x2 W[4][12];
#pragma unroll
    for (int g = 0; g < 4; ++g) {
        const float* wr = w_hh + (g * HH + j) * HH + 24 * s;
#pragma unroll
        for (int m = 0; m < 12; ++m)
            W[g][m] = f16x2{(_Float16)wr[2 * m], (_Float16)wr[2 * m + 1]};
    }
#pragma unroll
    for (int g = 0; g < 4; ++g)
#pragma unroll
        for (int m = 0; m < 12; ++m) asm volatile("" : "+v"(W[g][m]));

    // Per-thread gate-s constants (bias added AFTER the butterfly reduce).
    const float wih_s  = w_ih[s * HH + j];
    const float bias_s = b_ih[s * HH + j] + b_hh[s * HH + j];
    const float a_scale = (s == 2) ? 2.0f : 1.0f;   // tanh gate is s==2
    const float a_mul   = (s == 2) ? 2.0f : 1.0f;
    const float a_add   = (s == 2) ? -1.0f : 0.0f;

    const float fcb = fc_b[0];
    float c = 0.0f;   // valid on s==0 lanes only

    for (int i = tid; i < HH; i += TH) {
        fcw_s[i] = fc_w[i];
        hist[(NS - 1) * ROWP + i] = (_Float16)0.0f;  // h(-1) = 0
    }

    // Bulk fc projection for steps [t0, t0+NS): out = hist.fcw + fcb + x
    auto flush = [&](int t0) {
        for (int i = tid; i < NS; i += TH) {
            const uint2* hr = (const uint2*)(hist + i * ROWP);
            float a = 0.0f;
#pragma unroll
            for (int m = 0; m < 24; ++m) {
                uint2 u = hr[m];
                f16x2 p0 = __builtin_bit_cast(f16x2, u.x);
                f16x2 p1 = __builtin_bit_cast(f16x2, u.y);
                a = fmaf((float)p0.x, fcw_s[4 * m + 0], a);
                a = fmaf((float)p0.y, fcw_s[4 * m + 1], a);
                a = fmaf((float)p1.x, fcw_s[4 * m + 2], a);
                a = fmaf((float)p1.y, fcw_s[4 * m + 3], a);
            }
            out[(t0 + i) * BB + b] = a + fcb + xs[(t0 + i) & (CH - 1)];
        }
    };

    for (int t = 0; t < TT; ++t) {
        if (t > 0 && (t & (NS - 1)) == 0) {   // flush BEFORE any xs refill
            flush(t - NS);
            __syncthreads();
        }
        if ((t & (CH - 1)) == 0) {            // covers t=0 (also init barrier)
            for (int i = tid; i < CH; i += TH) xs[i] = x[(t + i) * BB + b];
            __syncthreads();
        }

        // ---- h(t-1) slice: 3 x ds_read_b128 (16B-aligned) ----
        const int pr = (t - 1) & (NS - 1);    // t=0 -> 511 (zeros)
        const uint4* hrow = (const uint4*)(hist + pr * ROWP + 24 * s);
        uint4 u0 = hrow[0], u1 = hrow[1], u2 = hrow[2];
        f16x2 h2[12] = {
            __builtin_bit_cast(f16x2, u0.x), __builtin_bit_cast(f16x2, u0.y),
            __builtin_bit_cast(f16x2, u0.z), __builtin_bit_cast(f16x2, u0.w),
            __builtin_bit_cast(f16x2, u1.x), __builtin_bit_cast(f16x2, u1.y),
            __builtin_bit_cast(f16x2, u1.z), __builtin_bit_cast(f16x2, u1.w),
            __builtin_bit_cast(f16x2, u2.x), __builtin_bit_cast(f16x2, u2.y),
            __builtin_bit_cast(f16x2, u2.z), __builtin_bit_cast(f16x2, u2.w)};
        const float xv = xs[t & (CH - 1)];

        // ---- 4 gates x 12 dots (2 parallel chains of 6 each) ----
        float acc[4];
#pragma unroll
        for (int g = 0; g < 4; ++g) {
            float e0 = 0.0f, e1 = 0.0f;
#pragma unroll
            for (int m = 0; m < 6; ++m) e0 = dot2_f16(W[g][m], h2[m], e0);
#pragma unroll
            for (int m = 6; m < 12; ++m) e1 = dot2_f16(W[g][m], h2[m], e1);
            acc[g] = e0 + e1;
        }

        // ---- 2-level quad butterfly: every lane gets all 4 gate sums ----
#pragma unroll
        for (int g = 0; g < 4; ++g) {
            acc[g] = dpp_add<DPP_XOR1>(acc[g]);
            acc[g] = dpp_add<DPP_XOR2>(acc[g]);
        }

        // ---- lane s handles gate s: select, bias, activation ----
        float pre = acc[0];
        pre = (s == 1) ? acc[1] : pre;
        pre = (s == 2) ? acc[2] : pre;
        pre = (s == 3) ? acc[3] : pre;
        pre += fmaf(xv, wih_s, bias_s);
        const float act =
            fmaf(__builtin_amdgcn_rcpf(1.0f + __expf(-pre * a_scale)), a_mul, a_add);

        // ---- gather f,g,o to lane 0; c/h update (valid on s==0) ----
        const float fv = dpp_bcast<DPP_B1>(act);
        const float gv = dpp_bcast<DPP_B2>(act);
        const float ov = dpp_bcast<DPP_B3>(act);
        c = fmaf(fv, c, act * gv);          // on s==0: act == i-gate
        const float h = ov * tanh_f(c);
        if ((tid & 3) == 0) hist[(t & (NS - 1)) * ROWP + j] = (_Float16)h;
        __syncthreads();   // h(t) visible; hist row reuse safe
    }
    flush(TT - NS);        // last window (loop ended with a barrier)
}

extern "C" void kernel_launch(void* const* d_in, const int* in_sizes, int n_in,
                              void* d_out, int out_size, void* d_ws, size_t ws_size,
                              hipStream_t stream) {
    const float* x    = (const float*)d_in[0];
    const float* w_ih = (const float*)d_in[1];
    const float* w_hh = (const float*)d_in[2];
    const float* b_ih = (const float*)d_in[3];
    const float* b_hh = (const float*)d_in[4];
    const float* fc_w = (const float*)d_in[5];
    const float* fc_b = (const float*)d_in[6];
    float* out = (float*)d_out;

    lstm_kernel<<<dim3(BB), dim3(TH), 0, stream>>>(x, w_ih, w_hh, b_ih, b_hh,
                                                   fc_w, fc_b, out);
}